// Round 2
// baseline (87.605 us; speedup 1.0000x reference)
//
#include <hip/hip_runtime.h>

// SNN binary classifier, fused single kernel. B=4096, D=256, H=512, O=2, T=100.
// Block = 1024 threads (16 waves) handles BM=16 batch rows; grid = 256 = 1 block/CU,
// 16 waves/CU = 4 waves/SIMD (50% occupancy) to hide VALU dependency latency.
//   Phase 1: h1 = x @ W1^T + b1 into LDS. Thread (col=tid>>1, rhalf=tid&1)
//            computes 1 h-column for 8 rows; k-loop order bit-identical to the
//            R1 passing kernel so h1/s1 trajectories are unchanged.
//   Phase 2: LIF recurrence. 1 row per wave, 64 lanes, 8 h-elems/lane.
//            Per-step 64-lane reduce: 4x DPP row_ror + row_bcast15 + row_bcast31
//            (pure VALU, no LDS). Lane 48 holds the full sum and writes.

#define BM 16
#define LDS_H_STRIDE 520   // 512 + 8 pad

template <int CTRL>
__device__ __forceinline__ float dpp_add(float v) {
    int x = __builtin_amdgcn_update_dpp(0, __builtin_bit_cast(int, v),
                                        CTRL, 0xF, 0xF, false);
    return v + __builtin_bit_cast(float, x);
}

__global__ __launch_bounds__(1024, 4) void snn_fused_kernel(
    const float* __restrict__ x,   // [4096,256]
    const float* __restrict__ W1,  // [512,256]
    const float* __restrict__ b1,  // [512]
    const float* __restrict__ W2,  // [2,512]
    const float* __restrict__ b2,  // [2]
    const int* __restrict__ tsp,   // [1]
    float* __restrict__ out)       // [4096,2]
{
    __shared__ float xs[BM * 256];            // 16 KiB
    __shared__ float h1s[BM * LDS_H_STRIDE];  // ~32.5 KiB

    const int tid  = threadIdx.x;
    const int row0 = blockIdx.x * BM;

    // ---- stage x rows (coalesced float4, one per thread) ----
    ((float4*)xs)[tid] = ((const float4*)(x + (size_t)row0 * 256))[tid];
    __syncthreads();

    // ---- Phase 1: 1 h-column x 8 rows per thread ----
    {
        const int col = tid >> 1;          // 0..511 (lane pairs share a W1 row)
        const int rb  = (tid & 1) * 8;     // row half: 0 or 8
        float acc[8];
        const float bias = b1[col];
        #pragma unroll
        for (int b = 0; b < 8; ++b) acc[b] = bias;

        const float4* wv  = (const float4*)(W1 + (size_t)col * 256);
        const float4* xsv = (const float4*)xs;

        float4 w = wv[0];
        #pragma unroll 1
        for (int k4 = 0; k4 < 64; ++k4) {
            const int kn = (k4 < 63) ? k4 + 1 : 63;   // prefetch next W1 chunk
            float4 wn = wv[kn];
            float4 xv[8];
            #pragma unroll
            for (int b = 0; b < 8; ++b) xv[b] = xsv[(rb + b) * 64 + k4]; // broadcast
            #pragma unroll
            for (int b = 0; b < 8; ++b) {
                acc[b] = fmaf(xv[b].x, w.x, acc[b]);
                acc[b] = fmaf(xv[b].y, w.y, acc[b]);
                acc[b] = fmaf(xv[b].z, w.z, acc[b]);
                acc[b] = fmaf(xv[b].w, w.w, acc[b]);
            }
            w = wn;
        }
        #pragma unroll
        for (int b = 0; b < 8; ++b)
            h1s[(rb + b) * LDS_H_STRIDE + col] = acc[b];
    }
    __syncthreads();

    // ---- Phase 2: LIF recurrence, 1 row per wave ----
    {
        const int l    = tid & 63;
        const int wid  = tid >> 6;         // 0..15 = local row
        const int row  = row0 + wid;

        float hv[8], w0r[8], w1r[8], mem[8];
        #pragma unroll
        for (int j = 0; j < 8; ++j) {
            const int h = l + j * 64;      // consecutive lanes -> consecutive LDS
            hv[j]  = h1s[wid * LDS_H_STRIDE + h];
            w0r[j] = W2[h];
            w1r[j] = W2[512 + h];
            mem[j] = 0.0f;
        }
        const float bb0 = b2[0], bb1 = b2[1];
        const int   T   = tsp[0];

        float c0 = 0.0f, c1 = 0.0f;
        for (int t = 0; t < T; ++t) {
            float a0 = 0.0f, a1 = 0.0f, a0b = 0.0f, a1b = 0.0f;
            #pragma unroll
            for (int j = 0; j < 8; j += 2) {
                // membrane update non-fused to match reference algebra exactly
                float m0 = __fadd_rn(__fmul_rn(0.9f, mem[j]),     hv[j]);
                float m1 = __fadd_rn(__fmul_rn(0.9f, mem[j + 1]), hv[j + 1]);
                float s0 = (m0 > 1.0f) ? 1.0f : 0.0f;
                float s1 = (m1 > 1.0f) ? 1.0f : 0.0f;
                mem[j]     = m0 - s0;
                mem[j + 1] = m1 - s1;
                a0  = fmaf(s0, w0r[j],     a0);
                a1  = fmaf(s0, w1r[j],     a1);
                a0b = fmaf(s1, w0r[j + 1], a0b);
                a1b = fmaf(s1, w1r[j + 1], a1b);
            }
            a0 += a0b; a1 += a1b;
            // 64-lane reduce, pure VALU DPP:
            a0 = dpp_add<0x121>(a0); a1 = dpp_add<0x121>(a1);  // ror 1
            a0 = dpp_add<0x122>(a0); a1 = dpp_add<0x122>(a1);  // ror 2
            a0 = dpp_add<0x124>(a0); a1 = dpp_add<0x124>(a1);  // ror 4
            a0 = dpp_add<0x128>(a0); a1 = dpp_add<0x128>(a1);  // ror 8
            a0 = dpp_add<0x142>(a0); a1 = dpp_add<0x142>(a1);  // row_bcast15
            a0 = dpp_add<0x143>(a0); a1 = dpp_add<0x143>(a1);  // row_bcast31
            // lanes 48..63 now hold the full 512-sum
            c0 += ((a0 + bb0) > 0.0f) ? 1.0f : 0.0f;
            c1 += ((a1 + bb1) > 0.0f) ? 1.0f : 0.0f;
        }

        if (l == 48) {
            const float ft = (float)T;
            float2* dst = (float2*)(out + (size_t)row * 2);
            *dst = make_float2(c0 / ft, c1 / ft);
        }
    }
}

extern "C" void kernel_launch(void* const* d_in, const int* in_sizes, int n_in,
                              void* d_out, int out_size, void* d_ws, size_t ws_size,
                              hipStream_t stream) {
    const float* x   = (const float*)d_in[0];
    const float* W1  = (const float*)d_in[1];
    const float* b1  = (const float*)d_in[2];
    const float* W2  = (const float*)d_in[3];
    const float* b2  = (const float*)d_in[4];
    const int*   tsp = (const int*)d_in[5];
    float*       out = (float*)d_out;

    const int B = in_sizes[0] / 256;          // 4096
    snn_fused_kernel<<<dim3(B / BM), dim3(1024), 0, stream>>>(
        x, W1, b1, W2, b2, tsp, out);
}